// Round 1
// baseline (2253.852 us; speedup 1.0000x reference)
//
#include <hip/hip_runtime.h>
#include <hip/hip_bf16.h>

// Problem constants (DecoderRNN): B=64, S=64, IMG_F=2048, EMB=HID=512, VOCAB=32000
#define B_    64
#define S_    64
#define T_    63      // S-1
#define IMGF  2048
#define EMB   512
#define HID   512
#define VOCAB 32000
#define MROWS 4032    // B_*T_
#define MPAD  4096    // padded to multiple of 128

typedef __bf16 bf16;
typedef __bf16 bf16x8 __attribute__((ext_vector_type(8)));
typedef float  f32x4  __attribute__((ext_vector_type(4)));

__device__ __forceinline__ void gload_lds16(const void* g, void* l) {
  __builtin_amdgcn_global_load_lds(
      (const __attribute__((address_space(1))) unsigned int*)g,
      (__attribute__((address_space(3))) unsigned int*)l, 16, 0, 0);
}

// ---------------------------------------------------------------------------
// Tiled transpose f32[K][N] -> bf16[N][K]  (64x64 tiles via LDS)
// ---------------------------------------------------------------------------
__global__ __launch_bounds__(256) void transpose_w(
    const float* __restrict__ W, bf16* __restrict__ WT, int K, int N)
{
  __shared__ float tile[64][65];
  const int tx = threadIdx.x & 63, ty = threadIdx.x >> 6;
  const int n0 = blockIdx.x * 64, k0 = blockIdx.y * 64;
  #pragma unroll
  for (int r = ty; r < 64; r += 4)
    tile[r][tx] = W[(size_t)(k0 + r) * N + n0 + tx];
  __syncthreads();
  #pragma unroll
  for (int r = ty; r < 64; r += 4)
    WT[(size_t)(n0 + r) * K + k0 + tx] = (bf16)tile[tx][r];
}

// ---------------------------------------------------------------------------
// Embedding gather: X[r][e] = embed_W[captions[b, t]][e], r = b*63+t, bf16 out
// rows >= MROWS zero-padded
// ---------------------------------------------------------------------------
__global__ __launch_bounds__(256) void embed_gather(
    const float* __restrict__ embW, const int* __restrict__ captions,
    bf16* __restrict__ X)
{
  const int r = blockIdx.x;
  const int tid = threadIdx.x;
  if (r < MROWS) {
    const int b = r / T_, t = r % T_;            // t in [0,62]
    const int idx = captions[b * S_ + t];
    float2 v = ((const float2*)(embW + (size_t)idx * EMB))[tid];
    X[(size_t)r * EMB + 2 * tid]     = (bf16)v.x;
    X[(size_t)r * EMB + 2 * tid + 1] = (bf16)v.y;
  } else {
    X[(size_t)r * EMB + 2 * tid]     = (bf16)0.f;
    X[(size_t)r * EMB + 2 * tid + 1] = (bf16)0.f;
  }
}

// ---------------------------------------------------------------------------
// bf16 MFMA GEMM: C[m][n] = sum_k A[m][k]*BT[n][k] + bias[n]   (f32 out)
// A: [Mtiles*128][K] bf16 row-major, BT: [N][K] bf16, N % 128 == 0, K % 32 == 0
// 128x128 tile, BK=32, 4 waves (2x2, each 64x64 = 4x4 frags of 16x16x32)
// LDS XOR-swizzle on 16B slots: slot_phys = slot_log ^ ((row>>1)&3)
// ---------------------------------------------------------------------------
__global__ __launch_bounds__(256) void gemm_bt(
    const bf16* __restrict__ A, const bf16* __restrict__ BT,
    const float* __restrict__ bias, float* __restrict__ C,
    int Mvalid, int N, int K)
{
  __shared__ __align__(16) bf16 As[128 * 32];
  __shared__ __align__(16) bf16 Bs[128 * 32];
  const int tid  = threadIdx.x;
  const int wave = tid >> 6, lane = tid & 63;
  const int wm = wave >> 1, wn = wave & 1;
  const int bn = blockIdx.x, bm = blockIdx.y;
  const int lg = lane >> 4, lr = lane & 15;

  f32x4 acc[4][4];
  #pragma unroll
  for (int m = 0; m < 4; m++)
    #pragma unroll
    for (int n = 0; n < 4; n++) acc[m][n] = (f32x4){0.f, 0.f, 0.f, 0.f};

  const bf16* Abase = A  + (size_t)bm * 128 * K;
  const bf16* Bbase = BT + (size_t)bn * 128 * K;

  for (int kt = 0; kt < K; kt += 32) {
    __syncthreads();
    #pragma unroll
    for (int i = 0; i < 2; i++) {
      const int c = i * 256 + wave * 64 + lane;       // 16B chunk id (512 total)
      const int r = c >> 2;
      const int sl = (c & 3) ^ ((r >> 1) & 3);        // logical slot for phys chunk
      gload_lds16(Abase + (size_t)r * K + kt + sl * 8,
                  &As[(i * 256 + wave * 64) * 8]);
    }
    #pragma unroll
    for (int i = 0; i < 2; i++) {
      const int c = i * 256 + wave * 64 + lane;
      const int r = c >> 2;
      const int sl = (c & 3) ^ ((r >> 1) & 3);
      gload_lds16(Bbase + (size_t)r * K + kt + sl * 8,
                  &Bs[(i * 256 + wave * 64) * 8]);
    }
    __syncthreads();

    bf16x8 af[4], bfr[4];
    #pragma unroll
    for (int m = 0; m < 4; m++) {
      const int r = wm * 64 + m * 16 + lr;
      const int sp = lg ^ ((r >> 1) & 3);
      af[m] = *(const bf16x8*)&As[r * 32 + sp * 8];
    }
    #pragma unroll
    for (int n = 0; n < 4; n++) {
      const int r = wn * 64 + n * 16 + lr;
      const int sp = lg ^ ((r >> 1) & 3);
      bfr[n] = *(const bf16x8*)&Bs[r * 32 + sp * 8];
    }
    #pragma unroll
    for (int m = 0; m < 4; m++)
      #pragma unroll
      for (int n = 0; n < 4; n++)
        acc[m][n] = __builtin_amdgcn_mfma_f32_16x16x32_bf16(af[m], bfr[n], acc[m][n], 0, 0, 0);
  }

  // C/D layout (measured, m89/m91): col = lane&15, row = (lane>>4)*4 + reg
  const int row0 = bm * 128 + wm * 64 + (lane >> 4) * 4;
  const int col0 = bn * 128 + wn * 64 + lr;
  #pragma unroll
  for (int m = 0; m < 4; m++) {
    #pragma unroll
    for (int n = 0; n < 4; n++) {
      const int col = col0 + n * 16;
      const float bv = bias[col];
      #pragma unroll
      for (int q = 0; q < 4; q++) {
        const int row = row0 + m * 16 + q;
        if (row < Mvalid) C[(size_t)row * N + col] = acc[m][n][q] + bv;
      }
    }
  }
}

// ---------------------------------------------------------------------------
// pre[b*63+0][:] += img[b] @ Wi + bi      (f32, one block per batch row)
// ---------------------------------------------------------------------------
__global__ __launch_bounds__(256) void img_proj(
    const float* __restrict__ img, const float* __restrict__ Wi,
    const float* __restrict__ bi, float* __restrict__ pre)
{
  const int b = blockIdx.x, tid = threadIdx.x;
  __shared__ float sh[IMGF];
  for (int i = tid; i < IMGF; i += 256) sh[i] = img[(size_t)b * IMGF + i];
  __syncthreads();
  #pragma unroll
  for (int o = 0; o < 2; o++) {
    const int h = tid + o * 256;
    float s = bi[h];
    #pragma unroll 4
    for (int k = 0; k < IMGF; k++) s = fmaf(sh[k], Wi[(size_t)k * HID + h], s);
    pre[(size_t)(b * T_) * HID + h] += s;
  }
}

// ---------------------------------------------------------------------------
// One RNN step (f32): h_next[b] = tanh(pre[b,t] + h_prev[b] @ Wh + bh)
// also emits bf16 copy into hs for the logits GEMM
// ---------------------------------------------------------------------------
__global__ __launch_bounds__(256) void rnn_step(
    const float* __restrict__ pre, const float* __restrict__ Wh,
    const float* __restrict__ bh, const float* __restrict__ hp,
    float* __restrict__ hn, bf16* __restrict__ hs, int t)
{
  const int b = blockIdx.x, tid = threadIdx.x;
  __shared__ float sh[HID];
  sh[tid]       = hp[(size_t)b * HID + tid];
  sh[tid + 256] = hp[(size_t)b * HID + tid + 256];
  __syncthreads();
  const size_t rowoff = (size_t)(b * T_ + t) * HID;
  #pragma unroll
  for (int o = 0; o < 2; o++) {
    const int h = tid + o * 256;
    float s = pre[rowoff + h] + bh[h];
    #pragma unroll 8
    for (int k = 0; k < HID; k++) s = fmaf(sh[k], Wh[(size_t)k * HID + h], s);
    const float hv = tanhf(s);
    hn[(size_t)b * HID + h] = hv;
    hs[rowoff + h] = (bf16)hv;
  }
}

// ---------------------------------------------------------------------------
extern "C" void kernel_launch(void* const* d_in, const int* in_sizes, int n_in,
                              void* d_out, int out_size, void* d_ws, size_t ws_size,
                              hipStream_t stream) {
  const float* img      = (const float*)d_in[0];
  const int*   captions = (const int*)d_in[1];
  const float* embW     = (const float*)d_in[2];
  const float* Wi       = (const float*)d_in[3];
  const float* bi       = (const float*)d_in[4];
  const float* Wx       = (const float*)d_in[5];
  const float* bx       = (const float*)d_in[6];
  const float* Wh       = (const float*)d_in[7];
  const float* bh       = (const float*)d_in[8];
  const float* Wy       = (const float*)d_in[9];
  const float* by       = (const float*)d_in[10];
  float* logits = (float*)d_out;

  // workspace layout (~50.2 MB total)
  char* ws = (char*)d_ws;
  bf16*  WyT = (bf16*)(ws);                    // 32000*512*2 = 32,768,000
  bf16*  WxT = (bf16*)(ws + 32768000);         //   512*512*2 =    524,288
  bf16*  X   = (bf16*)(ws + 33292288);         //  4096*512*2 =  4,194,304
  bf16*  hs  = (bf16*)(ws + 37486592);         //  4096*512*2 =  4,194,304
  float* pre = (float*)(ws + 41680896);        //  4032*512*4 =  8,257,536
  float* hA  = (float*)(ws + 49938432);        //    64*512*4 =    131,072
  float* hB  = (float*)(ws + 50069504);        //    64*512*4 =    131,072

  // 1) weight transposes to bf16 [N][K]
  transpose_w<<<dim3(VOCAB / 64, HID / 64), 256, 0, stream>>>(Wy, WyT, HID, VOCAB);
  transpose_w<<<dim3(HID / 64, EMB / 64), 256, 0, stream>>>(Wx, WxT, EMB, HID);

  // 2) embedding gather (bf16, padded to 4096 rows)
  embed_gather<<<MPAD, 256, 0, stream>>>(embW, captions, X);

  // 3) pre = X @ Wx + bx
  gemm_bt<<<dim3(HID / 128, MPAD / 128), 256, 0, stream>>>(X, WxT, bx, pre, MROWS, HID, HID);

  // 4) pre[:,0] += img @ Wi + bi
  img_proj<<<B_, 256, 0, stream>>>(img, Wi, bi, pre);

  // 5) RNN: h0 = 0; zero hs pad rows
  hipMemsetAsync(hA, 0, (size_t)B_ * HID * sizeof(float), stream);
  hipMemsetAsync(hs + (size_t)MROWS * HID, 0,
                 (size_t)(MPAD - MROWS) * HID * sizeof(bf16), stream);
  float* hcur = hA; float* hnext = hB;
  for (int t = 0; t < T_; t++) {
    rnn_step<<<B_, 256, 0, stream>>>(pre, Wh, bh, hcur, hnext, hs, t);
    float* tmp = hcur; hcur = hnext; hnext = tmp;
  }

  // 6) logits = hs @ Wy + by
  gemm_bt<<<dim3(VOCAB / 128, MPAD / 128), 256, 0, stream>>>(hs, WyT, by, logits, MROWS, VOCAB, HID);
}

// Round 2
// 872.664 us; speedup vs baseline: 2.5827x; 2.5827x over previous
//
#include <hip/hip_runtime.h>
#include <hip/hip_bf16.h>

// Problem constants (DecoderRNN): B=64, S=64, IMG_F=2048, EMB=HID=512, VOCAB=32000
#define B_    64
#define S_    64
#define T_    63      // S-1
#define IMGF  2048
#define EMB   512
#define HID   512
#define VOCAB 32000
#define MROWS 4032    // B_*T_
#define MPAD  4096    // padded to multiple of 128

typedef __bf16 bf16;
typedef __bf16 bf16x8 __attribute__((ext_vector_type(8)));
typedef float  f32x4  __attribute__((ext_vector_type(4)));

__device__ __forceinline__ void gload_lds16(const void* g, void* l) {
  __builtin_amdgcn_global_load_lds(
      (const __attribute__((address_space(1))) unsigned int*)g,
      (__attribute__((address_space(3))) unsigned int*)l, 16, 0, 0);
}

// ---------------------------------------------------------------------------
// Tiled transpose f32[K][N] -> bf16[N][K]  (64x64 tiles via LDS)
// ---------------------------------------------------------------------------
__global__ __launch_bounds__(256) void transpose_w(
    const float* __restrict__ W, bf16* __restrict__ WT, int K, int N)
{
  __shared__ float tile[64][65];
  const int tx = threadIdx.x & 63, ty = threadIdx.x >> 6;
  const int n0 = blockIdx.x * 64, k0 = blockIdx.y * 64;
  #pragma unroll
  for (int r = ty; r < 64; r += 4)
    tile[r][tx] = W[(size_t)(k0 + r) * N + n0 + tx];
  __syncthreads();
  #pragma unroll
  for (int r = ty; r < 64; r += 4)
    WT[(size_t)(n0 + r) * K + k0 + tx] = (bf16)tile[tx][r];
}

// ---------------------------------------------------------------------------
// Embedding gather: X[r][e] = embed_W[captions[b, t]][e], r = b*63+t, bf16 out
// rows >= MROWS zero-padded
// ---------------------------------------------------------------------------
__global__ __launch_bounds__(256) void embed_gather(
    const float* __restrict__ embW, const int* __restrict__ captions,
    bf16* __restrict__ X)
{
  const int r = blockIdx.x;
  const int tid = threadIdx.x;
  if (r < MROWS) {
    const int b = r / T_, t = r % T_;            // t in [0,62]
    const int idx = captions[b * S_ + t];
    float2 v = ((const float2*)(embW + (size_t)idx * EMB))[tid];
    X[(size_t)r * EMB + 2 * tid]     = (bf16)v.x;
    X[(size_t)r * EMB + 2 * tid + 1] = (bf16)v.y;
  } else {
    X[(size_t)r * EMB + 2 * tid]     = (bf16)0.f;
    X[(size_t)r * EMB + 2 * tid + 1] = (bf16)0.f;
  }
}

// ---------------------------------------------------------------------------
// img -> bf16, padded to 128 rows
// ---------------------------------------------------------------------------
__global__ __launch_bounds__(256) void img_to_bf16(
    const float* __restrict__ img, bf16* __restrict__ imgB)
{
  const int r = blockIdx.x;          // 0..127
  const int tid = threadIdx.x;
  #pragma unroll
  for (int j = 0; j < 8; j++) {
    const int c = tid + j * 256;     // 0..2047
    const float v = (r < B_) ? img[(size_t)r * IMGF + c] : 0.f;
    imgB[(size_t)r * IMGF + c] = (bf16)v;
  }
}

// ---------------------------------------------------------------------------
// bf16 MFMA GEMM: C[m][n] = sum_k A[m][k]*BT[n][k] + bias[n]   (f32 out)
// A: [Mtiles*128][K] bf16 row-major, BT: [N][K] bf16, N % 128 == 0, K % 32 == 0
// 128x128 tile, BK=32, 4 waves (2x2, each 64x64 = 4x4 frags of 16x16x32)
// LDS XOR-swizzle on 16B slots: slot_phys = slot_log ^ ((row>>1)&3)
// ---------------------------------------------------------------------------
__global__ __launch_bounds__(256) void gemm_bt(
    const bf16* __restrict__ A, const bf16* __restrict__ BT,
    const float* __restrict__ bias, float* __restrict__ C,
    int Mvalid, int N, int K)
{
  __shared__ __align__(16) bf16 As[128 * 32];
  __shared__ __align__(16) bf16 Bs[128 * 32];
  const int tid  = threadIdx.x;
  const int wave = tid >> 6, lane = tid & 63;
  const int wm = wave >> 1, wn = wave & 1;
  const int bn = blockIdx.x, bm = blockIdx.y;
  const int lg = lane >> 4, lr = lane & 15;

  f32x4 acc[4][4];
  #pragma unroll
  for (int m = 0; m < 4; m++)
    #pragma unroll
    for (int n = 0; n < 4; n++) acc[m][n] = (f32x4){0.f, 0.f, 0.f, 0.f};

  const bf16* Abase = A  + (size_t)bm * 128 * K;
  const bf16* Bbase = BT + (size_t)bn * 128 * K;

  for (int kt = 0; kt < K; kt += 32) {
    __syncthreads();
    #pragma unroll
    for (int i = 0; i < 2; i++) {
      const int c = i * 256 + wave * 64 + lane;       // 16B chunk id (512 total)
      const int r = c >> 2;
      const int sl = (c & 3) ^ ((r >> 1) & 3);        // logical slot for phys chunk
      gload_lds16(Abase + (size_t)r * K + kt + sl * 8,
                  &As[(i * 256 + wave * 64) * 8]);
    }
    #pragma unroll
    for (int i = 0; i < 2; i++) {
      const int c = i * 256 + wave * 64 + lane;
      const int r = c >> 2;
      const int sl = (c & 3) ^ ((r >> 1) & 3);
      gload_lds16(Bbase + (size_t)r * K + kt + sl * 8,
                  &Bs[(i * 256 + wave * 64) * 8]);
    }
    __syncthreads();

    bf16x8 af[4], bfr[4];
    #pragma unroll
    for (int m = 0; m < 4; m++) {
      const int r = wm * 64 + m * 16 + lr;
      const int sp = lg ^ ((r >> 1) & 3);
      af[m] = *(const bf16x8*)&As[r * 32 + sp * 8];
    }
    #pragma unroll
    for (int n = 0; n < 4; n++) {
      const int r = wn * 64 + n * 16 + lr;
      const int sp = lg ^ ((r >> 1) & 3);
      bfr[n] = *(const bf16x8*)&Bs[r * 32 + sp * 8];
    }
    #pragma unroll
    for (int m = 0; m < 4; m++)
      #pragma unroll
      for (int n = 0; n < 4; n++)
        acc[m][n] = __builtin_amdgcn_mfma_f32_16x16x32_bf16(af[m], bfr[n], acc[m][n], 0, 0, 0);
  }

  // C/D layout (measured, m89/m91): col = lane&15, row = (lane>>4)*4 + reg
  const int row0 = bm * 128 + wm * 64 + (lane >> 4) * 4;
  const int col0 = bn * 128 + wn * 64 + lr;
  #pragma unroll
  for (int m = 0; m < 4; m++) {
    #pragma unroll
    for (int n = 0; n < 4; n++) {
      const int col = col0 + n * 16;
      const float bv = bias[col];
      #pragma unroll
      for (int q = 0; q < 4; q++) {
        const int row = row0 + m * 16 + q;
        if (row < Mvalid) C[(size_t)row * N + col] = acc[m][n][q] + bv;
      }
    }
  }
}

// ---------------------------------------------------------------------------
// Persistent RNN: one block per batch row, all 63 steps in-kernel.
// h kept in LDS (f32); Wh read from L2 (f32, float4-coalesced);
// 512 threads: kq = tid>>7 (k-quarter), hg = tid&127 (4-col group).
// Two barriers per step.
// ---------------------------------------------------------------------------
__global__ __launch_bounds__(512) void rnn_all(
    const float* __restrict__ pre, const float* __restrict__ Wh,
    const float* __restrict__ bh, const float* __restrict__ pimg,
    bf16* __restrict__ hs)
{
  const int b = blockIdx.x, tid = threadIdx.x;
  const int kq = tid >> 7, hg = tid & 127;
  const int c0 = hg * 4;
  __shared__ float hsh[HID];
  __shared__ float red[4][HID];
  hsh[tid & (HID - 1)] = 0.f;                 // h0 = 0 (512 threads cover 512)
  const float bhc = bh[tid];                  // col = tid in reduce phase
  const float pic = pimg[(size_t)b * HID + tid];
  __syncthreads();

  const float* WhQ = Wh + (size_t)kq * 128 * HID + c0;
  for (int t = 0; t < T_; t++) {
    f32x4 acc = (f32x4){0.f, 0.f, 0.f, 0.f};
    #pragma unroll 8
    for (int k = 0; k < 128; k++) {
      const float hv = hsh[kq * 128 + k];
      const f32x4 w = *(const f32x4*)(WhQ + (size_t)k * HID);
      acc[0] = fmaf(hv, w[0], acc[0]);
      acc[1] = fmaf(hv, w[1], acc[1]);
      acc[2] = fmaf(hv, w[2], acc[2]);
      acc[3] = fmaf(hv, w[3], acc[3]);
    }
    *(f32x4*)&red[kq][c0] = acc;
    __syncthreads();                           // A: all hsh reads + red writes done

    const size_t row = (size_t)(b * T_ + t) * HID;
    float s = red[0][tid] + red[1][tid] + red[2][tid] + red[3][tid]
            + pre[row + tid] + bhc;
    if (t == 0) s += pic;
    const float hv = tanhf(s);
    hsh[tid] = hv;                             // safe: hsh reads done before A
    hs[row + tid] = (bf16)hv;
    __syncthreads();                           // B: hsh/red ready for next step
  }
}

// ---------------------------------------------------------------------------
extern "C" void kernel_launch(void* const* d_in, const int* in_sizes, int n_in,
                              void* d_out, int out_size, void* d_ws, size_t ws_size,
                              hipStream_t stream) {
  const float* img      = (const float*)d_in[0];
  const int*   captions = (const int*)d_in[1];
  const float* embW     = (const float*)d_in[2];
  const float* Wi       = (const float*)d_in[3];
  const float* bi       = (const float*)d_in[4];
  const float* Wx       = (const float*)d_in[5];
  const float* bx       = (const float*)d_in[6];
  const float* Wh       = (const float*)d_in[7];
  const float* bh       = (const float*)d_in[8];
  const float* Wy       = (const float*)d_in[9];
  const float* by       = (const float*)d_in[10];
  float* logits = (float*)d_out;

  // workspace layout (~52.8 MB total)
  char* ws = (char*)d_ws;
  bf16*  WyT  = (bf16*)(ws);                   // 32000*512*2 = 32,768,000
  bf16*  WxT  = (bf16*)(ws + 32768000);        //   512*512*2 =    524,288
  bf16*  X    = (bf16*)(ws + 33292288);        //  4096*512*2 =  4,194,304
  bf16*  hs   = (bf16*)(ws + 37486592);        //  4096*512*2 =  4,194,304
  float* pre  = (float*)(ws + 41680896);       //  4032*512*4 =  8,257,536
  float* pimg = (float*)(ws + 49938432);       //   128*512*4 =    262,144
  bf16*  imgB = (bf16*)(ws + 50200576);        //  128*2048*2 =    524,288
  bf16*  WiT  = (bf16*)(ws + 50724864);        //  512*2048*2 =  2,097,152

  // 1) weight transposes / converts to bf16
  transpose_w<<<dim3(VOCAB / 64, HID / 64), 256, 0, stream>>>(Wy, WyT, HID, VOCAB);
  transpose_w<<<dim3(HID / 64, EMB / 64), 256, 0, stream>>>(Wx, WxT, EMB, HID);
  transpose_w<<<dim3(HID / 64, IMGF / 64), 256, 0, stream>>>(Wi, WiT, IMGF, HID);
  img_to_bf16<<<128, 256, 0, stream>>>(img, imgB);

  // 2) embedding gather (bf16, padded to 4096 rows)
  embed_gather<<<MPAD, 256, 0, stream>>>(embW, captions, X);

  // 3) pre = X @ Wx + bx
  gemm_bt<<<dim3(HID / 128, MPAD / 128), 256, 0, stream>>>(X, WxT, bx, pre, MROWS, HID, HID);

  // 4) pimg = img @ Wi + bi   (added into step t=0 inside rnn_all)
  gemm_bt<<<dim3(HID / 128, 1), 256, 0, stream>>>(imgB, WiT, bi, pimg, B_, HID, IMGF);

  // 5) RNN: all 63 steps, one persistent kernel (64 independent batch chains)
  hipMemsetAsync(hs + (size_t)MROWS * HID, 0,
                 (size_t)(MPAD - MROWS) * HID * sizeof(bf16), stream);
  rnn_all<<<B_, 512, 0, stream>>>(pre, Wh, bh, pimg, hs);

  // 6) logits = hs @ Wy + by
  gemm_bt<<<dim3(VOCAB / 128, MPAD / 128), 256, 0, stream>>>(hs, WyT, by, logits, MROWS, VOCAB, HID);
}

// Round 3
// 861.406 us; speedup vs baseline: 2.6165x; 1.0131x over previous
//
#include <hip/hip_runtime.h>
#include <hip/hip_bf16.h>

// Problem constants (DecoderRNN): B=64, S=64, IMG_F=2048, EMB=HID=512, VOCAB=32000
#define B_    64
#define S_    64
#define T_    63      // S-1
#define IMGF  2048
#define EMB   512
#define HID   512
#define VOCAB 32000
#define MROWS 4032    // B_*T_
#define MPAD  4096    // padded to multiple of 128

typedef __bf16 bf16;
typedef __bf16 bf16x2 __attribute__((ext_vector_type(2)));
typedef __bf16 bf16x8 __attribute__((ext_vector_type(8)));
typedef float  f32x4  __attribute__((ext_vector_type(4)));

__device__ __forceinline__ void gload_lds16(const void* g, void* l) {
  __builtin_amdgcn_global_load_lds(
      (const __attribute__((address_space(1))) unsigned int*)g,
      (__attribute__((address_space(3))) unsigned int*)l, 16, 0, 0);
}

// ---------------------------------------------------------------------------
// Tiled transpose f32[K][N] -> bf16[N][K]  (64x64 tiles via LDS)
// ---------------------------------------------------------------------------
__global__ __launch_bounds__(256) void transpose_w(
    const float* __restrict__ W, bf16* __restrict__ WT, int K, int N)
{
  __shared__ float tile[64][65];
  const int tx = threadIdx.x & 63, ty = threadIdx.x >> 6;
  const int n0 = blockIdx.x * 64, k0 = blockIdx.y * 64;
  #pragma unroll
  for (int r = ty; r < 64; r += 4)
    tile[r][tx] = W[(size_t)(k0 + r) * N + n0 + tx];
  __syncthreads();
  #pragma unroll
  for (int r = ty; r < 64; r += 4)
    WT[(size_t)(n0 + r) * K + k0 + tx] = (bf16)tile[tx][r];
}

// ---------------------------------------------------------------------------
// Embedding gather: X[r][e] = embed_W[captions[b, t]][e], r = b*63+t, bf16 out
// ---------------------------------------------------------------------------
__global__ __launch_bounds__(256) void embed_gather(
    const float* __restrict__ embW, const int* __restrict__ captions,
    bf16* __restrict__ X)
{
  const int r = blockIdx.x;
  const int tid = threadIdx.x;
  if (r < MROWS) {
    const int b = r / T_, t = r % T_;            // t in [0,62]
    const int idx = captions[b * S_ + t];
    float2 v = ((const float2*)(embW + (size_t)idx * EMB))[tid];
    X[(size_t)r * EMB + 2 * tid]     = (bf16)v.x;
    X[(size_t)r * EMB + 2 * tid + 1] = (bf16)v.y;
  } else {
    X[(size_t)r * EMB + 2 * tid]     = (bf16)0.f;
    X[(size_t)r * EMB + 2 * tid + 1] = (bf16)0.f;
  }
}

// ---------------------------------------------------------------------------
// img -> bf16, padded to 128 rows
// ---------------------------------------------------------------------------
__global__ __launch_bounds__(256) void img_to_bf16(
    const float* __restrict__ img, bf16* __restrict__ imgB)
{
  const int r = blockIdx.x;          // 0..127
  const int tid = threadIdx.x;
  #pragma unroll
  for (int j = 0; j < 8; j++) {
    const int c = tid + j * 256;     // 0..2047
    const float v = (r < B_) ? img[(size_t)r * IMGF + c] : 0.f;
    imgB[(size_t)r * IMGF + c] = (bf16)v;
  }
}

// ---------------------------------------------------------------------------
// bf16 MFMA GEMM (unchanged from round 2): C = A @ BT^T + bias, f32 out
// ---------------------------------------------------------------------------
__global__ __launch_bounds__(256) void gemm_bt(
    const bf16* __restrict__ A, const bf16* __restrict__ BT,
    const float* __restrict__ bias, float* __restrict__ C,
    int Mvalid, int N, int K)
{
  __shared__ __align__(16) bf16 As[128 * 32];
  __shared__ __align__(16) bf16 Bs[128 * 32];
  const int tid  = threadIdx.x;
  const int wave = tid >> 6, lane = tid & 63;
  const int wm = wave >> 1, wn = wave & 1;
  const int bn = blockIdx.x, bm = blockIdx.y;
  const int lg = lane >> 4, lr = lane & 15;

  f32x4 acc[4][4];
  #pragma unroll
  for (int m = 0; m < 4; m++)
    #pragma unroll
    for (int n = 0; n < 4; n++) acc[m][n] = (f32x4){0.f, 0.f, 0.f, 0.f};

  const bf16* Abase = A  + (size_t)bm * 128 * K;
  const bf16* Bbase = BT + (size_t)bn * 128 * K;

  for (int kt = 0; kt < K; kt += 32) {
    __syncthreads();
    #pragma unroll
    for (int i = 0; i < 2; i++) {
      const int c = i * 256 + wave * 64 + lane;       // 16B chunk id (512 total)
      const int r = c >> 2;
      const int sl = (c & 3) ^ ((r >> 1) & 3);        // logical slot for phys chunk
      gload_lds16(Abase + (size_t)r * K + kt + sl * 8,
                  &As[(i * 256 + wave * 64) * 8]);
    }
    #pragma unroll
    for (int i = 0; i < 2; i++) {
      const int c = i * 256 + wave * 64 + lane;
      const int r = c >> 2;
      const int sl = (c & 3) ^ ((r >> 1) & 3);
      gload_lds16(Bbase + (size_t)r * K + kt + sl * 8,
                  &Bs[(i * 256 + wave * 64) * 8]);
    }
    __syncthreads();

    bf16x8 af[4], bfr[4];
    #pragma unroll
    for (int m = 0; m < 4; m++) {
      const int r = wm * 64 + m * 16 + lr;
      const int sp = lg ^ ((r >> 1) & 3);
      af[m] = *(const bf16x8*)&As[r * 32 + sp * 8];
    }
    #pragma unroll
    for (int n = 0; n < 4; n++) {
      const int r = wn * 64 + n * 16 + lr;
      const int sp = lg ^ ((r >> 1) & 3);
      bfr[n] = *(const bf16x8*)&Bs[r * 32 + sp * 8];
    }
    #pragma unroll
    for (int m = 0; m < 4; m++)
      #pragma unroll
      for (int n = 0; n < 4; n++)
        acc[m][n] = __builtin_amdgcn_mfma_f32_16x16x32_bf16(af[m], bfr[n], acc[m][n], 0, 0, 0);
  }

  const int row0 = bm * 128 + wm * 64 + (lane >> 4) * 4;
  const int col0 = bn * 128 + wn * 64 + lr;
  #pragma unroll
  for (int m = 0; m < 4; m++) {
    #pragma unroll
    for (int n = 0; n < 4; n++) {
      const int col = col0 + n * 16;
      const float bv = bias[col];
      #pragma unroll
      for (int q = 0; q < 4; q++) {
        const int row = row0 + m * 16 + q;
        if (row < Mvalid) C[(size_t)row * N + col] = acc[m][n][q] + bv;
      }
    }
  }
}

// ---------------------------------------------------------------------------
// Persistent RNN, MFMA edition.
// Grid: 32 blocks = 4 groups (16 batches each) x 8 col-blocks (64 cols each).
// Wh slice staged ONCE in LDS (bf16, 64 KB) -> zero L2 Wh traffic per step.
// Per step: stage h[16][512] (bf16, swizzled) from exchange buf, 16x64 tile
// via mfma_16x16x32 (one n-frag per wave), tanh, write hs + exchange, then
// 8-block group barrier (agent-scope atomics; data moves via atomic ld/st,
// coherent across XCDs).
// LDS chunk swizzle: phys_chunk = log_chunk ^ (row & 7)  (16B chunks,
// row stride 1 KB -> spreads 16 frag rows over all 32 banks).
// ---------------------------------------------------------------------------
__global__ __launch_bounds__(256) void rnn_mfma(
    const float* __restrict__ pre, const bf16* __restrict__ WhT,
    const float* __restrict__ bh, const float* __restrict__ pimg,
    bf16* __restrict__ hs, float* ex, unsigned* cnt)
{
  const int bx  = blockIdx.x;
  const int grp = bx >> 3, cb = bx & 7;
  const int tid = threadIdx.x;
  const int wave = tid >> 6, lane = tid & 63;
  const int lg = lane >> 4, lr = lane & 15;
  const int gb0 = grp * 16;           // first batch of group
  const int gc0 = cb * 64;            // first col owned by this block

  __shared__ __align__(16) bf16 hsh[16 * 512];   // h   [batch][k]
  __shared__ __align__(16) bf16 wsh[64 * 512];   // WhT [local col][k]

  // ---- stage Wh slice once (coalesced bf16x8 from WhT rows) ----
  #pragma unroll
  for (int i = 0; i < 16; i++) {
    const int ch = tid + i * 256;               // 0..4095 (64 rows x 64 chunks)
    const int r = ch >> 6, l = ch & 63;
    const bf16x8 v = *(const bf16x8*)(WhT + (size_t)(gc0 + r) * 512 + l * 8);
    *(bf16x8*)&wsh[(r * 64 + (l ^ (r & 7))) * 8] = v;
  }

  // per-lane output coordinates & constants
  const int lc = wave * 16 + lr;                // local col 0..63
  const int cg = gc0 + lc;                      // global col
  const int bq0 = lg * 4;                       // first of 4 batch rows
  const float bhv = bh[cg];
  float piv[4];
  #pragma unroll
  for (int q = 0; q < 4; q++)
    piv[q] = pimg[(size_t)(gb0 + bq0 + q) * HID + cg];

  __syncthreads();

  for (int t = 0; t < T_; t++) {
    // ---- prefetch pre values for this step (independent of h) ----
    float prq[4];
    #pragma unroll
    for (int q = 0; q < 4; q++)
      prq[q] = pre[(size_t)((gb0 + bq0 + q) * T_ + t) * HID + cg];

    // ---- stage h from exchange buffer (agent-scope atomic u64 loads) ----
    const float* exr = ex + (size_t)(t & 1) * B_ * HID;
    #pragma unroll
    for (int i = 0; i < 16; i++) {
      const int u = tid + i * 256;              // 0..4095 (16 batches x 256 pairs)
      const int b = u >> 8, p = u & 255;
      const int c = p * 2;
      unsigned long long raw = __hip_atomic_load(
          (const unsigned long long*)(exr + (size_t)(gb0 + b) * HID + c),
          __ATOMIC_RELAXED, __HIP_MEMORY_SCOPE_AGENT);
      bf16x2 pr;
      pr[0] = (bf16)__uint_as_float((unsigned)raw);
      pr[1] = (bf16)__uint_as_float((unsigned)(raw >> 32));
      const int l = c >> 3;
      *(bf16x2*)&hsh[(b * 64 + (l ^ (b & 7))) * 8 + (c & 7)] = pr;
    }
    __syncthreads();

    // ---- 16x64 tile: each wave one 16x16 n-frag, K=512 ----
    f32x4 acc0 = (f32x4){0.f, 0.f, 0.f, 0.f};
    f32x4 acc1 = (f32x4){0.f, 0.f, 0.f, 0.f};
    #pragma unroll
    for (int ks = 0; ks < 16; ks += 2) {
      const int la0 = ks * 4 + lg, la1 = (ks + 1) * 4 + lg;
      bf16x8 a0 = *(const bf16x8*)&hsh[(lr * 64 + (la0 ^ (lr & 7))) * 8];
      bf16x8 b0 = *(const bf16x8*)&wsh[(lc * 64 + (la0 ^ (lc & 7))) * 8];
      bf16x8 a1 = *(const bf16x8*)&hsh[(lr * 64 + (la1 ^ (lr & 7))) * 8];
      bf16x8 b1 = *(const bf16x8*)&wsh[(lc * 64 + (la1 ^ (lc & 7))) * 8];
      acc0 = __builtin_amdgcn_mfma_f32_16x16x32_bf16(a0, b0, acc0, 0, 0, 0);
      acc1 = __builtin_amdgcn_mfma_f32_16x16x32_bf16(a1, b1, acc1, 0, 0, 0);
    }

    // ---- epilogue: tanh, write hs (bf16) + exchange (atomic f32) ----
    float* exw = ex + (size_t)((t + 1) & 1) * B_ * HID;
    #pragma unroll
    for (int q = 0; q < 4; q++) {
      const int b = gb0 + bq0 + q;
      const size_t row = (size_t)(b * T_ + t);
      float s = acc0[q] + acc1[q] + prq[q] + bhv;
      if (t == 0) s += piv[q];
      const float e = __builtin_exp2f(s * 2.885390081777927f);   // e^(2s)
      const float hv = 1.f - 2.f / (e + 1.f);                     // tanh(s)
      hs[row * HID + cg] = (bf16)hv;
      __hip_atomic_store((unsigned*)(exw + (size_t)b * HID + cg),
                         __float_as_uint(hv),
                         __ATOMIC_RELAXED, __HIP_MEMORY_SCOPE_AGENT);
    }

    // ---- group barrier: 8 blocks, release-RMW / acquire-spin ----
    __syncthreads();   // drains all lanes' stores (vmcnt 0 before s_barrier)
    if (tid == 0) {
      __hip_atomic_fetch_add(&cnt[grp * 32], 1u,
                             __ATOMIC_RELEASE, __HIP_MEMORY_SCOPE_AGENT);
      const unsigned tgt = 8u * (unsigned)(t + 1);
      while (__hip_atomic_load(&cnt[grp * 32],
                               __ATOMIC_ACQUIRE, __HIP_MEMORY_SCOPE_AGENT) < tgt)
        __builtin_amdgcn_s_sleep(1);
    }
    __syncthreads();
  }
}

// ---------------------------------------------------------------------------
extern "C" void kernel_launch(void* const* d_in, const int* in_sizes, int n_in,
                              void* d_out, int out_size, void* d_ws, size_t ws_size,
                              hipStream_t stream) {
  const float* img      = (const float*)d_in[0];
  const int*   captions = (const int*)d_in[1];
  const float* embW     = (const float*)d_in[2];
  const float* Wi       = (const float*)d_in[3];
  const float* bi       = (const float*)d_in[4];
  const float* Wx       = (const float*)d_in[5];
  const float* bx       = (const float*)d_in[6];
  const float* Wh       = (const float*)d_in[7];
  const float* bh       = (const float*)d_in[8];
  const float* Wy       = (const float*)d_in[9];
  const float* by       = (const float*)d_in[10];
  float* logits = (float*)d_out;

  // workspace layout (52.8 MB, same footprint as round 2; WhT/ex/cnt alias
  // regions that are dead after the pre-GEMM — stream order protects)
  char* ws = (char*)d_ws;
  bf16*  WyT  = (bf16*)(ws);                   // 32000*512*2 = 32,768,000
  bf16*  WxT  = (bf16*)(ws + 32768000);        //   512*512*2 =    524,288
  bf16*  X    = (bf16*)(ws + 33292288);        //  4096*512*2 =  4,194,304
  bf16*  hs   = (bf16*)(ws + 37486592);        //  4096*512*2 =  4,194,304
  float* pre  = (float*)(ws + 41680896);       //  4032*512*4 =  8,257,536
  float* pimg = (float*)(ws + 49938432);       //   128*512*4 =    262,144
  bf16*  imgB = (bf16*)(ws + 50200576);        //  128*2048*2 =    524,288
  bf16*  WiT  = (bf16*)(ws + 50724864);        //  512*2048*2 =  2,097,152
  // aliases (used only after pre-GEMM):
  bf16*     WhT = WxT;                         // 512*512*2 = 524,288 (over WxT)
  float*    ex  = (float*)(ws + 33292288);     // 2*64*512*4 = 262,144 (over X)
  unsigned* cnt = (unsigned*)(ws + 33292288 + 262144);  // 512 B (over X)

  // 1) weight transposes / converts to bf16
  transpose_w<<<dim3(VOCAB / 64, HID / 64), 256, 0, stream>>>(Wy, WyT, HID, VOCAB);
  transpose_w<<<dim3(HID / 64, EMB / 64), 256, 0, stream>>>(Wx, WxT, EMB, HID);
  transpose_w<<<dim3(HID / 64, IMGF / 64), 256, 0, stream>>>(Wi, WiT, IMGF, HID);
  img_to_bf16<<<128, 256, 0, stream>>>(img, imgB);

  // 2) embedding gather (bf16, padded to 4096 rows)
  embed_gather<<<MPAD, 256, 0, stream>>>(embW, captions, X);

  // 3) pre = X @ Wx + bx   (last reader of X / WxT)
  gemm_bt<<<dim3(HID / 128, MPAD / 128), 256, 0, stream>>>(X, WxT, bx, pre, MROWS, HID, HID);

  // 4) pimg = img @ Wi + bi
  gemm_bt<<<dim3(HID / 128, 1), 256, 0, stream>>>(imgB, WiT, bi, pimg, B_, HID, IMGF);

  // 5) Wh -> bf16 [col][k] into the (now dead) WxT slot
  transpose_w<<<dim3(HID / 64, HID / 64), 256, 0, stream>>>(Wh, WhT, HID, HID);

  // 6) init exchange buffer 0 (= h0 = 0), barrier counters, hs pad rows
  hipMemsetAsync(ex, 0, (size_t)B_ * HID * sizeof(float), stream);
  hipMemsetAsync(cnt, 0, 512, stream);
  hipMemsetAsync(hs + (size_t)MROWS * HID, 0,
                 (size_t)(MPAD - MROWS) * HID * sizeof(bf16), stream);

  // 7) RNN: all 63 steps, 32 blocks (4 groups x 8 col-blocks)
  rnn_mfma<<<32, 256, 0, stream>>>(pre, WhT, bh, pimg, hs, ex, cnt);

  // 8) logits = hs @ Wy + by
  gemm_bt<<<dim3(VOCAB / 128, MPAD / 128), 256, 0, stream>>>(hs, WyT, by, logits, MROWS, VOCAB, HID);
}

// Round 4
// 765.219 us; speedup vs baseline: 2.9454x; 1.1257x over previous
//
#include <hip/hip_runtime.h>
#include <hip/hip_bf16.h>

// Problem constants (DecoderRNN): B=64, S=64, IMG_F=2048, EMB=HID=512, VOCAB=32000
#define B_    64
#define S_    64
#define T_    63      // S-1
#define IMGF  2048
#define EMB   512
#define HID   512
#define VOCAB 32000
#define MROWS 4032    // B_*T_
#define MPAD  4096    // padded to multiple of 128

typedef __bf16 bf16;
typedef __bf16 bf16x8 __attribute__((ext_vector_type(8)));
typedef float  f32x4  __attribute__((ext_vector_type(4)));

__device__ __forceinline__ void gload_lds16(const void* g, void* l) {
  __builtin_amdgcn_global_load_lds(
      (const __attribute__((address_space(1))) unsigned int*)g,
      (__attribute__((address_space(3))) unsigned int*)l, 16, 0, 0);
}

// ---------------------------------------------------------------------------
// Tiled transpose f32[K][N] -> bf16[N][K]  (64x64 tiles via LDS)
// ---------------------------------------------------------------------------
__global__ __launch_bounds__(256) void transpose_w(
    const float* __restrict__ W, bf16* __restrict__ WT, int K, int N)
{
  __shared__ float tile[64][65];
  const int tx = threadIdx.x & 63, ty = threadIdx.x >> 6;
  const int n0 = blockIdx.x * 64, k0 = blockIdx.y * 64;
  #pragma unroll
  for (int r = ty; r < 64; r += 4)
    tile[r][tx] = W[(size_t)(k0 + r) * N + n0 + tx];
  __syncthreads();
  #pragma unroll
  for (int r = ty; r < 64; r += 4)
    WT[(size_t)(n0 + r) * K + k0 + tx] = (bf16)tile[tx][r];
}

// ---------------------------------------------------------------------------
// Embedding gather: X[r][e] = embed_W[captions[b, t]][e], r = b*63+t, bf16 out
// ---------------------------------------------------------------------------
__global__ __launch_bounds__(256) void embed_gather(
    const float* __restrict__ embW, const int* __restrict__ captions,
    bf16* __restrict__ X)
{
  const int r = blockIdx.x;
  const int tid = threadIdx.x;
  if (r < MROWS) {
    const int b = r / T_, t = r % T_;            // t in [0,62]
    const int idx = captions[b * S_ + t];
    float2 v = ((const float2*)(embW + (size_t)idx * EMB))[tid];
    X[(size_t)r * EMB + 2 * tid]     = (bf16)v.x;
    X[(size_t)r * EMB + 2 * tid + 1] = (bf16)v.y;
  } else {
    X[(size_t)r * EMB + 2 * tid]     = (bf16)0.f;
    X[(size_t)r * EMB + 2 * tid + 1] = (bf16)0.f;
  }
}

// ---------------------------------------------------------------------------
// img -> bf16, padded to 128 rows
// ---------------------------------------------------------------------------
__global__ __launch_bounds__(256) void img_to_bf16(
    const float* __restrict__ img, bf16* __restrict__ imgB)
{
  const int r = blockIdx.x;          // 0..127
  const int tid = threadIdx.x;
  #pragma unroll
  for (int j = 0; j < 8; j++) {
    const int c = tid + j * 256;     // 0..2047
    const float v = (r < B_) ? img[(size_t)r * IMGF + c] : 0.f;
    imgB[(size_t)r * IMGF + c] = (bf16)v;
  }
}

// ---------------------------------------------------------------------------
// bf16 MFMA GEMM (unchanged): C = A @ BT^T + bias, f32 out
// ---------------------------------------------------------------------------
__global__ __launch_bounds__(256) void gemm_bt(
    const bf16* __restrict__ A, const bf16* __restrict__ BT,
    const float* __restrict__ bias, float* __restrict__ C,
    int Mvalid, int N, int K)
{
  __shared__ __align__(16) bf16 As[128 * 32];
  __shared__ __align__(16) bf16 Bs[128 * 32];
  const int tid  = threadIdx.x;
  const int wave = tid >> 6, lane = tid & 63;
  const int wm = wave >> 1, wn = wave & 1;
  const int bn = blockIdx.x, bm = blockIdx.y;
  const int lg = lane >> 4, lr = lane & 15;

  f32x4 acc[4][4];
  #pragma unroll
  for (int m = 0; m < 4; m++)
    #pragma unroll
    for (int n = 0; n < 4; n++) acc[m][n] = (f32x4){0.f, 0.f, 0.f, 0.f};

  const bf16* Abase = A  + (size_t)bm * 128 * K;
  const bf16* Bbase = BT + (size_t)bn * 128 * K;

  for (int kt = 0; kt < K; kt += 32) {
    __syncthreads();
    #pragma unroll
    for (int i = 0; i < 2; i++) {
      const int c = i * 256 + wave * 64 + lane;       // 16B chunk id (512 total)
      const int r = c >> 2;
      const int sl = (c & 3) ^ ((r >> 1) & 3);        // logical slot for phys chunk
      gload_lds16(Abase + (size_t)r * K + kt + sl * 8,
                  &As[(i * 256 + wave * 64) * 8]);
    }
    #pragma unroll
    for (int i = 0; i < 2; i++) {
      const int c = i * 256 + wave * 64 + lane;
      const int r = c >> 2;
      const int sl = (c & 3) ^ ((r >> 1) & 3);
      gload_lds16(Bbase + (size_t)r * K + kt + sl * 8,
                  &Bs[(i * 256 + wave * 64) * 8]);
    }
    __syncthreads();

    bf16x8 af[4], bfr[4];
    #pragma unroll
    for (int m = 0; m < 4; m++) {
      const int r = wm * 64 + m * 16 + lr;
      const int sp = lg ^ ((r >> 1) & 3);
      af[m] = *(const bf16x8*)&As[r * 32 + sp * 8];
    }
    #pragma unroll
    for (int n = 0; n < 4; n++) {
      const int r = wn * 64 + n * 16 + lr;
      const int sp = lg ^ ((r >> 1) & 3);
      bfr[n] = *(const bf16x8*)&Bs[r * 32 + sp * 8];
    }
    #pragma unroll
    for (int m = 0; m < 4; m++)
      #pragma unroll
      for (int n = 0; n < 4; n++)
        acc[m][n] = __builtin_amdgcn_mfma_f32_16x16x32_bf16(af[m], bfr[n], acc[m][n], 0, 0, 0);
  }

  const int row0 = bm * 128 + wm * 64 + (lane >> 4) * 4;
  const int col0 = bn * 128 + wn * 64 + lr;
  #pragma unroll
  for (int m = 0; m < 4; m++) {
    #pragma unroll
    for (int n = 0; n < 4; n++) {
      const int col = col0 + n * 16;
      const float bv = bias[col];
      #pragma unroll
      for (int q = 0; q < 4; q++) {
        const int row = row0 + m * 16 + q;
        if (row < Mvalid) C[(size_t)row * N + col] = acc[m][n][q] + bv;
      }
    }
  }
}

// ---------------------------------------------------------------------------
// Persistent RNN, register-resident Wh edition.
// Grid: 4 blocks x 256 threads (4 waves, 1 wave/SIMD, 512-VGPR budget).
// Each block: 16 batches, FULL 512-col recurrence -> zero inter-block comm.
// Wh (bf16, [col][k]) split per wave (128 cols): 128 frags of 16x32;
//   frags f=0..92 in VGPRs (372 regs), f=93..127 in LDS (35 KB/wave).
// h in LDS [batch][k] (16 KB), XOR-swizzled 16B chunks: phys = c ^ (batch&7).
// Per step: 16 A-frag + 35 B-frag ds_read_b128, 128 MFMA, tanh epilogue,
// 2 intra-CU barriers. pre prefetched into regs at step start.
// ---------------------------------------------------------------------------
__global__ __launch_bounds__(256, 1) void rnn_reg(
    const float* __restrict__ pre, const bf16* __restrict__ WhT,
    const float* __restrict__ bh, const float* __restrict__ pimg,
    bf16* __restrict__ hs)
{
  const int bg  = blockIdx.x;          // batch group 0..3
  const int tid = threadIdx.x;
  const int wave = tid >> 6, lane = tid & 63;
  const int lg = lane >> 4, lr = lane & 15;
  const int gb0 = bg * 16;             // first batch of block
  const int wc0 = wave * 128;          // first col of wave

  __shared__ __align__(16) bf16 hsh[16 * 512];        // 16 KB, [batch][k] swizzled
  __shared__ __align__(16) bf16 bls[140 * 64 * 8];    // 140 KB: 35 frags x 4 waves

  // ---- stage Wh: 128 frags per wave; f = n*16 + kf ----
  bf16x8 bw[93];
  #pragma unroll
  for (int f = 0; f < 128; f++) {
    const int n = f >> 4, kf = f & 15;
    const int col = wc0 + n * 16 + lr;
    const bf16x8 v = *(const bf16x8*)(WhT + (size_t)col * 512 + kf * 32 + lg * 8);
    if (f < 93) bw[f] = v;
    else *(bf16x8*)&bls[((wave * 35 + (f - 93)) * 64 + lane) * 8] = v;
  }

  // ---- h0 = 0 (each thread zeroes 64 B) ----
  #pragma unroll
  for (int i = 0; i < 4; i++)
    *(f32x4*)&hsh[tid * 32 + i * 8] = (f32x4){0.f, 0.f, 0.f, 0.f};

  // per-lane constants
  float bhv[8];
  #pragma unroll
  for (int n = 0; n < 8; n++) bhv[n] = bh[wc0 + n * 16 + lr];
  const float* preb = pre + ((size_t)(gb0 + lg * 4) * T_) * 512 + wc0 + lr;

  __syncthreads();

  #pragma unroll 1
  for (int t = 0; t < T_; t++) {
    // ---- prefetch pre for this step (independent of h; hides under MFMA) ----
    float prq[8][4];
    #pragma unroll
    for (int n = 0; n < 8; n++)
      #pragma unroll
      for (int q = 0; q < 4; q++)
        prq[n][q] = preb[(size_t)q * (T_ * 512) + (size_t)t * 512 + n * 16];

    f32x4 acc[8];
    #pragma unroll
    for (int n = 0; n < 8; n++) acc[n] = (f32x4){0.f, 0.f, 0.f, 0.f};

    // ---- 128 MFMAs: k in quarters, 4 A-frags live ----
    #pragma unroll
    for (int kq = 0; kq < 4; kq++) {
      bf16x8 a[4];
      #pragma unroll
      for (int j = 0; j < 4; j++) {
        const int kf = kq * 4 + j;
        const int c = (kf * 4 + lg) ^ (lr & 7);       // swizzled 16B chunk
        a[j] = *(const bf16x8*)&hsh[(lr * 64 + c) * 8];
      }
      #pragma unroll
      for (int j = 0; j < 4; j++) {
        const int kf = kq * 4 + j;
        #pragma unroll
        for (int n = 0; n < 8; n++) {
          const int f = n * 16 + kf;
          bf16x8 bfrag;
          if (f < 93) bfrag = bw[f];
          else bfrag = *(const bf16x8*)&bls[((wave * 35 + (f - 93)) * 64 + lane) * 8];
          acc[n] = __builtin_amdgcn_mfma_f32_16x16x32_bf16(a[j], bfrag, acc[n], 0, 0, 0);
        }
      }
    }
    __syncthreads();                  // all waves done READING hsh

    // ---- epilogue: tanh, write hs (global) + hsh (next step's A) ----
    #pragma unroll
    for (int n = 0; n < 8; n++) {
      #pragma unroll
      for (int q = 0; q < 4; q++) {
        const int bl = lg * 4 + q;                    // local batch
        const int b  = gb0 + bl;                      // global batch
        const int k  = wc0 + n * 16 + lr;             // output col
        float s = acc[n][q] + prq[n][q] + bhv[n];
        if (t == 0) s += pimg[(size_t)b * HID + k];
        const float e = __builtin_exp2f(s * 2.885390081777927f);  // e^(2s)
        const float hv = 1.f - 2.f / (e + 1.f);                    // tanh(s)
        hs[((size_t)b * T_ + t) * HID + k] = (bf16)hv;
        const int c = (k >> 3) ^ (bl & 7);
        hsh[bl * 512 + c * 8 + (k & 7)] = (bf16)hv;
      }
    }
    __syncthreads();                  // hsh ready for next step
  }
}

// ---------------------------------------------------------------------------
extern "C" void kernel_launch(void* const* d_in, const int* in_sizes, int n_in,
                              void* d_out, int out_size, void* d_ws, size_t ws_size,
                              hipStream_t stream) {
  const float* img      = (const float*)d_in[0];
  const int*   captions = (const int*)d_in[1];
  const float* embW     = (const float*)d_in[2];
  const float* Wi       = (const float*)d_in[3];
  const float* bi       = (const float*)d_in[4];
  const float* Wx       = (const float*)d_in[5];
  const float* bx       = (const float*)d_in[6];
  const float* Wh       = (const float*)d_in[7];
  const float* bh       = (const float*)d_in[8];
  const float* Wy       = (const float*)d_in[9];
  const float* by       = (const float*)d_in[10];
  float* logits = (float*)d_out;

  // workspace layout (52.8 MB; WhT aliases WxT which is dead after pre-GEMM)
  char* ws = (char*)d_ws;
  bf16*  WyT  = (bf16*)(ws);                   // 32000*512*2 = 32,768,000
  bf16*  WxT  = (bf16*)(ws + 32768000);        //   512*512*2 =    524,288
  bf16*  X    = (bf16*)(ws + 33292288);        //  4096*512*2 =  4,194,304
  bf16*  hs   = (bf16*)(ws + 37486592);        //  4096*512*2 =  4,194,304
  float* pre  = (float*)(ws + 41680896);       //  4032*512*4 =  8,257,536
  float* pimg = (float*)(ws + 49938432);       //   128*512*4 =    262,144
  bf16*  imgB = (bf16*)(ws + 50200576);        //  128*2048*2 =    524,288
  bf16*  WiT  = (bf16*)(ws + 50724864);        //  512*2048*2 =  2,097,152
  bf16*  WhT  = WxT;                           // alias: used only after pre-GEMM

  // 1) weight transposes / converts to bf16
  transpose_w<<<dim3(VOCAB / 64, HID / 64), 256, 0, stream>>>(Wy, WyT, HID, VOCAB);
  transpose_w<<<dim3(HID / 64, EMB / 64), 256, 0, stream>>>(Wx, WxT, EMB, HID);
  transpose_w<<<dim3(HID / 64, IMGF / 64), 256, 0, stream>>>(Wi, WiT, IMGF, HID);
  img_to_bf16<<<128, 256, 0, stream>>>(img, imgB);

  // 2) embedding gather (bf16, padded to 4096 rows)
  embed_gather<<<MPAD, 256, 0, stream>>>(embW, captions, X);

  // 3) pre = X @ Wx + bx   (last reader of X / WxT)
  gemm_bt<<<dim3(HID / 128, MPAD / 128), 256, 0, stream>>>(X, WxT, bx, pre, MROWS, HID, HID);

  // 4) pimg = img @ Wi + bi
  gemm_bt<<<dim3(HID / 128, 1), 256, 0, stream>>>(imgB, WiT, bi, pimg, B_, HID, IMGF);

  // 5) Wh -> bf16 [col][k] into the (now dead) WxT slot
  transpose_w<<<dim3(HID / 64, HID / 64), 256, 0, stream>>>(Wh, WhT, HID, HID);

  // 6) zero hs pad rows (read by logits GEMM)
  hipMemsetAsync(hs + (size_t)MROWS * HID, 0,
                 (size_t)(MPAD - MROWS) * HID * sizeof(bf16), stream);

  // 7) RNN: all 63 steps, 4 fully-independent blocks (16 batches each)
  rnn_reg<<<4, 256, 0, stream>>>(pre, WhT, bh, pimg, hs);

  // 8) logits = hs @ Wy + by
  gemm_bt<<<dim3(VOCAB / 128, MPAD / 128), 256, 0, stream>>>(hs, WyT, by, logits, MROWS, VOCAB, HID);
}

// Round 5
// 667.904 us; speedup vs baseline: 3.3745x; 1.1457x over previous
//
#include <hip/hip_runtime.h>
#include <hip/hip_bf16.h>

// Problem constants (DecoderRNN): B=64, S=64, IMG_F=2048, EMB=HID=512, VOCAB=32000
#define B_    64
#define S_    64
#define T_    63      // S-1
#define IMGF  2048
#define EMB   512
#define HID   512
#define VOCAB 32000
#define MROWS 4032    // B_*T_
#define MPAD  4096    // padded to multiple of 128

typedef __bf16 bf16;
typedef __bf16 bf16x8 __attribute__((ext_vector_type(8)));
typedef float  f32x4  __attribute__((ext_vector_type(4)));

__device__ __forceinline__ void gload_lds16(const void* g, void* l) {
  __builtin_amdgcn_global_load_lds(
      (const __attribute__((address_space(1))) unsigned int*)g,
      (__attribute__((address_space(3))) unsigned int*)l, 16, 0, 0);
}

// ---------------------------------------------------------------------------
// Tiled transpose f32[K][N] -> bf16[N][K]  (64x64 tiles via LDS)
// ---------------------------------------------------------------------------
__global__ __launch_bounds__(256) void transpose_w(
    const float* __restrict__ W, bf16* __restrict__ WT, int K, int N)
{
  __shared__ float tile[64][65];
  const int tx = threadIdx.x & 63, ty = threadIdx.x >> 6;
  const int n0 = blockIdx.x * 64, k0 = blockIdx.y * 64;
  #pragma unroll
  for (int r = ty; r < 64; r += 4)
    tile[r][tx] = W[(size_t)(k0 + r) * N + n0 + tx];
  __syncthreads();
  #pragma unroll
  for (int r = ty; r < 64; r += 4)
    WT[(size_t)(n0 + r) * K + k0 + tx] = (bf16)tile[tx][r];
}

// ---------------------------------------------------------------------------
// Embedding gather: X[r][e] = embed_W[captions[b, t]][e], r = b*63+t, bf16 out
// ---------------------------------------------------------------------------
__global__ __launch_bounds__(256) void embed_gather(
    const float* __restrict__ embW, const int* __restrict__ captions,
    bf16* __restrict__ X)
{
  const int r = blockIdx.x;
  const int tid = threadIdx.x;
  if (r < MROWS) {
    const int b = r / T_, t = r % T_;            // t in [0,62]
    const int idx = captions[b * S_ + t];
    float2 v = ((const float2*)(embW + (size_t)idx * EMB))[tid];
    X[(size_t)r * EMB + 2 * tid]     = (bf16)v.x;
    X[(size_t)r * EMB + 2 * tid + 1] = (bf16)v.y;
  } else {
    X[(size_t)r * EMB + 2 * tid]     = (bf16)0.f;
    X[(size_t)r * EMB + 2 * tid + 1] = (bf16)0.f;
  }
}

// ---------------------------------------------------------------------------
// img -> bf16, padded to 128 rows
// ---------------------------------------------------------------------------
__global__ __launch_bounds__(256) void img_to_bf16(
    const float* __restrict__ img, bf16* __restrict__ imgB)
{
  const int r = blockIdx.x;          // 0..127
  const int tid = threadIdx.x;
  #pragma unroll
  for (int j = 0; j < 8; j++) {
    const int c = tid + j * 256;     // 0..2047
    const float v = (r < B_) ? img[(size_t)r * IMGF + c] : 0.f;
    imgB[(size_t)r * IMGF + c] = (bf16)v;
  }
}

// ---------------------------------------------------------------------------
// bf16 MFMA GEMM (unchanged): C = A @ BT^T + bias, f32 out
// ---------------------------------------------------------------------------
__global__ __launch_bounds__(256) void gemm_bt(
    const bf16* __restrict__ A, const bf16* __restrict__ BT,
    const float* __restrict__ bias, float* __restrict__ C,
    int Mvalid, int N, int K)
{
  __shared__ __align__(16) bf16 As[128 * 32];
  __shared__ __align__(16) bf16 Bs[128 * 32];
  const int tid  = threadIdx.x;
  const int wave = tid >> 6, lane = tid & 63;
  const int wm = wave >> 1, wn = wave & 1;
  const int bn = blockIdx.x, bm = blockIdx.y;
  const int lg = lane >> 4, lr = lane & 15;

  f32x4 acc[4][4];
  #pragma unroll
  for (int m = 0; m < 4; m++)
    #pragma unroll
    for (int n = 0; n < 4; n++) acc[m][n] = (f32x4){0.f, 0.f, 0.f, 0.f};

  const bf16* Abase = A  + (size_t)bm * 128 * K;
  const bf16* Bbase = BT + (size_t)bn * 128 * K;

  for (int kt = 0; kt < K; kt += 32) {
    __syncthreads();
    #pragma unroll
    for (int i = 0; i < 2; i++) {
      const int c = i * 256 + wave * 64 + lane;       // 16B chunk id (512 total)
      const int r = c >> 2;
      const int sl = (c & 3) ^ ((r >> 1) & 3);        // logical slot for phys chunk
      gload_lds16(Abase + (size_t)r * K + kt + sl * 8,
                  &As[(i * 256 + wave * 64) * 8]);
    }
    #pragma unroll
    for (int i = 0; i < 2; i++) {
      const int c = i * 256 + wave * 64 + lane;
      const int r = c >> 2;
      const int sl = (c & 3) ^ ((r >> 1) & 3);
      gload_lds16(Bbase + (size_t)r * K + kt + sl * 8,
                  &Bs[(i * 256 + wave * 64) * 8]);
    }
    __syncthreads();

    bf16x8 af[4], bfr[4];
    #pragma unroll
    for (int m = 0; m < 4; m++) {
      const int r = wm * 64 + m * 16 + lr;
      const int sp = lg ^ ((r >> 1) & 3);
      af[m] = *(const bf16x8*)&As[r * 32 + sp * 8];
    }
    #pragma unroll
    for (int n = 0; n < 4; n++) {
      const int r = wn * 64 + n * 16 + lr;
      const int sp = lg ^ ((r >> 1) & 3);
      bfr[n] = *(const bf16x8*)&Bs[r * 32 + sp * 8];
    }
    #pragma unroll
    for (int m = 0; m < 4; m++)
      #pragma unroll
      for (int n = 0; n < 4; n++)
        acc[m][n] = __builtin_amdgcn_mfma_f32_16x16x32_bf16(af[m], bfr[n], acc[m][n], 0, 0, 0);
  }

  const int row0 = bm * 128 + wm * 64 + (lane >> 4) * 4;
  const int col0 = bn * 128 + wn * 64 + lr;
  #pragma unroll
  for (int m = 0; m < 4; m++) {
    #pragma unroll
    for (int n = 0; n < 4; n++) {
      const int col = col0 + n * 16;
      const float bv = bias[col];
      #pragma unroll
      for (int q = 0; q < 4; q++) {
        const int row = row0 + m * 16 + q;
        if (row < Mvalid) C[(size_t)row * N + col] = acc[m][n][q] + bv;
      }
    }
  }
}

// ---------------------------------------------------------------------------
// Persistent RNN, 8-wave edition (2 waves/SIMD for latency hiding).
// Grid: 4 blocks x 512 threads. Block = 16 batches, full 512-col recurrence,
// zero inter-block comm. Wave w owns cols [w*64, w*64+64): 64 B-frags of
// 16x32; frags f<47 in VGPRs (188 regs, fits 256-cap), f>=47 in LDS
// (17 frags/wave x 8 waves = 136 KB). h in LDS [batch][k] (16 KB),
// XOR-swizzled 16B chunks: phys = chunk ^ (batch&7). Total LDS 152 KB.
// Per step/wave: 16 A-frag reads, 17 B-frag reads, 64 MFMA, 16-col epilogue
// (exp2 + fast rcp), 2 barriers. pre prefetched at step start.
// ---------------------------------------------------------------------------
#define FREG 47
#define FLDS 17   // 64 - FREG
__global__ __launch_bounds__(512, 2) void rnn_reg8(
    const float* __restrict__ pre, const bf16* __restrict__ WhT,
    const float* __restrict__ bh, const float* __restrict__ pimg,
    bf16* __restrict__ hs)
{
  const int bg  = blockIdx.x;          // batch group 0..3
  const int tid = threadIdx.x;
  const int wave = tid >> 6, lane = tid & 63;
  const int lg = lane >> 4, lr = lane & 15;
  const int gb0 = bg * 16;             // first batch of block
  const int wc0 = wave * 64;           // first col of wave

  __shared__ __align__(16) bf16 hsh[16 * 512];              // 16 KB
  __shared__ __align__(16) bf16 bls[8 * FLDS * 64 * 8];     // 136 KB

  // ---- stage Wh: 64 frags per wave (f = n*16 + kf) ----
  bf16x8 bw[FREG];
  #pragma unroll
  for (int f = 0; f < 64; f++) {
    const int n = f >> 4, kf = f & 15;
    const bf16x8 v = *(const bf16x8*)(WhT + (size_t)(wc0 + n * 16 + lr) * 512
                                          + kf * 32 + lg * 8);
    if (f < FREG) bw[f] = v;
    else *(bf16x8*)&bls[((wave * FLDS + (f - FREG)) * 64 + lane) * 8] = v;
  }

  // ---- h0 = 0 (each thread zeroes 32 B) ----
  *(f32x4*)&hsh[tid * 16]     = (f32x4){0.f, 0.f, 0.f, 0.f};
  *(f32x4*)&hsh[tid * 16 + 8] = (f32x4){0.f, 0.f, 0.f, 0.f};

  // per-lane constants
  float bhv[4];
  #pragma unroll
  for (int n = 0; n < 4; n++) bhv[n] = bh[wc0 + n * 16 + lr];
  const float* preb = pre + ((size_t)(gb0 + lg * 4) * T_) * 512 + wc0 + lr;

  __syncthreads();

  #pragma unroll 1
  for (int t = 0; t < T_; t++) {
    // ---- prefetch pre for this step (independent of h; hides under MFMA) ----
    float prq[4][4];
    #pragma unroll
    for (int n = 0; n < 4; n++)
      #pragma unroll
      for (int q = 0; q < 4; q++)
        prq[n][q] = preb[(size_t)q * (T_ * 512) + (size_t)t * 512 + n * 16];

    f32x4 acc[4];
    #pragma unroll
    for (int n = 0; n < 4; n++) acc[n] = (f32x4){0.f, 0.f, 0.f, 0.f};

    // ---- 64 MFMAs over K=512 ----
    #pragma unroll
    for (int kf = 0; kf < 16; kf++) {
      const int c = (kf * 4 + lg) ^ (lr & 7);           // swizzled 16B chunk
      const bf16x8 a = *(const bf16x8*)&hsh[(lr * 64 + c) * 8];
      #pragma unroll
      for (int n = 0; n < 4; n++) {
        const int f = n * 16 + kf;
        bf16x8 bfrag;
        if (f < FREG) bfrag = bw[f];
        else bfrag = *(const bf16x8*)&bls[((wave * FLDS + (f - FREG)) * 64 + lane) * 8];
        acc[n] = __builtin_amdgcn_mfma_f32_16x16x32_bf16(a, bfrag, acc[n], 0, 0, 0);
      }
    }
    __syncthreads();                  // all waves done READING hsh

    // ---- epilogue: tanh, write hs (global) + hsh (next step's A) ----
    #pragma unroll
    for (int n = 0; n < 4; n++) {
      #pragma unroll
      for (int q = 0; q < 4; q++) {
        const int bl = lg * 4 + q;                      // local batch
        const int b  = gb0 + bl;                        // global batch
        const int k  = wc0 + n * 16 + lr;               // output col
        float s = acc[n][q] + prq[n][q] + bhv[n];
        if (t == 0) s += pimg[(size_t)b * HID + k];
        const float e = __builtin_exp2f(s * 2.885390081777927f);   // e^(2s)
        const float hv = 1.f - 2.f * __builtin_amdgcn_rcpf(e + 1.f); // tanh(s)
        hs[((size_t)b * T_ + t) * HID + k] = (bf16)hv;
        const int c = (k >> 3) ^ (bl & 7);
        hsh[bl * 512 + c * 8 + (k & 7)] = (bf16)hv;
      }
    }
    __syncthreads();                  // hsh ready for next step
  }
}

// ---------------------------------------------------------------------------
extern "C" void kernel_launch(void* const* d_in, const int* in_sizes, int n_in,
                              void* d_out, int out_size, void* d_ws, size_t ws_size,
                              hipStream_t stream) {
  const float* img      = (const float*)d_in[0];
  const int*   captions = (const int*)d_in[1];
  const float* embW     = (const float*)d_in[2];
  const float* Wi       = (const float*)d_in[3];
  const float* bi       = (const float*)d_in[4];
  const float* Wx       = (const float*)d_in[5];
  const float* bx       = (const float*)d_in[6];
  const float* Wh       = (const float*)d_in[7];
  const float* bh       = (const float*)d_in[8];
  const float* Wy       = (const float*)d_in[9];
  const float* by       = (const float*)d_in[10];
  float* logits = (float*)d_out;

  // workspace layout (52.8 MB; WhT aliases WxT which is dead after pre-GEMM)
  char* ws = (char*)d_ws;
  bf16*  WyT  = (bf16*)(ws);                   // 32000*512*2 = 32,768,000
  bf16*  WxT  = (bf16*)(ws + 32768000);        //   512*512*2 =    524,288
  bf16*  X    = (bf16*)(ws + 33292288);        //  4096*512*2 =  4,194,304
  bf16*  hs   = (bf16*)(ws + 37486592);        //  4096*512*2 =  4,194,304
  float* pre  = (float*)(ws + 41680896);       //  4032*512*4 =  8,257,536
  float* pimg = (float*)(ws + 49938432);       //   128*512*4 =    262,144
  bf16*  imgB = (bf16*)(ws + 50200576);        //  128*2048*2 =    524,288
  bf16*  WiT  = (bf16*)(ws + 50724864);        //  512*2048*2 =  2,097,152
  bf16*  WhT  = WxT;                           // alias: used only after pre-GEMM

  // 1) weight transposes / converts to bf16
  transpose_w<<<dim3(VOCAB / 64, HID / 64), 256, 0, stream>>>(Wy, WyT, HID, VOCAB);
  transpose_w<<<dim3(HID / 64, EMB / 64), 256, 0, stream>>>(Wx, WxT, EMB, HID);
  transpose_w<<<dim3(HID / 64, IMGF / 64), 256, 0, stream>>>(Wi, WiT, IMGF, HID);
  img_to_bf16<<<128, 256, 0, stream>>>(img, imgB);

  // 2) embedding gather (bf16, padded to 4096 rows)
  embed_gather<<<MPAD, 256, 0, stream>>>(embW, captions, X);

  // 3) pre = X @ Wx + bx   (last reader of X / WxT)
  gemm_bt<<<dim3(HID / 128, MPAD / 128), 256, 0, stream>>>(X, WxT, bx, pre, MROWS, HID, HID);

  // 4) pimg = img @ Wi + bi
  gemm_bt<<<dim3(HID / 128, 1), 256, 0, stream>>>(imgB, WiT, bi, pimg, B_, HID, IMGF);

  // 5) Wh -> bf16 [col][k] into the (now dead) WxT slot
  transpose_w<<<dim3(HID / 64, HID / 64), 256, 0, stream>>>(Wh, WhT, HID, HID);

  // 6) zero hs pad rows (read by logits GEMM)
  hipMemsetAsync(hs + (size_t)MROWS * HID, 0,
                 (size_t)(MPAD - MROWS) * HID * sizeof(bf16), stream);

  // 7) RNN: all 63 steps, 4 fully-independent blocks (16 batches each),
  //    8 waves/block = 2 waves/SIMD
  rnn_reg8<<<4, 512, 0, stream>>>(pre, WhT, bh, pimg, hs);

  // 8) logits = hs @ Wy + by
  gemm_bt<<<dim3(VOCAB / 128, MPAD / 128), 256, 0, stream>>>(hs, WyT, by, logits, MROWS, VOCAB, HID);
}